// Round 6
// baseline (738.412 us; speedup 1.0000x reference)
//
#include <hip/hip_runtime.h>

typedef __attribute__((ext_vector_type(4))) float f32x4;
typedef __attribute__((ext_vector_type(8))) short short8;

#define B_ 4
#define N_ 8192
#define E_ 131072
#define R_ 16
#define H_ 128
#define OUT_ 32
#define NKEYS (B_*N_*R_)   /* 524288 */
#define NEDGE (B_*E_)      /* 524288 */

__device__ __forceinline__ unsigned short f2bf(float f){
  unsigned int u = __float_as_uint(f);
  u = (u + 0x7fffu + ((u>>16)&1u)) >> 16;
  return (unsigned short)u;
}
__device__ __forceinline__ float bfh(unsigned u, int hi){
  return __uint_as_float(hi ? (u & 0xffff0000u) : (u << 16));
}
__device__ __forceinline__ unsigned cvtpk(float lo, float hi){
  unsigned r;
  asm("v_cvt_pk_bf16_f32 %0, %1, %2" : "=v"(r) : "v"(lo), "v"(hi));
  return r;
}

// ---------------- CSR build: key = ((b*16 + r)*8192 + dst) ----------------

__global__ void hist_k(const int* __restrict__ et, const int* __restrict__ ec,
                       int* __restrict__ cnt){
  int e = blockIdx.x*256 + threadIdx.x;
  int b = e >> 17;                  // E = 2^17
  int dst = et[2*e+1];
  int r  = ec[e];
  atomicAdd(&cnt[(((b<<4)+r)<<13) + dst], 1);
}

__global__ void scan1_k(const int* __restrict__ in, int* __restrict__ out,
                        int* __restrict__ bsum){
  __shared__ int lds[256];
  int t = threadIdx.x;
  int base = blockIdx.x*1024 + t*4;
  int4 v = *(const int4*)(in + base);
  lds[t] = v.x+v.y+v.z+v.w;
  __syncthreads();
  for (int off=1; off<256; off<<=1){
    int x = (t>=off) ? lds[t-off] : 0;
    __syncthreads();
    lds[t] += x;
    __syncthreads();
  }
  if (t==255) bsum[blockIdx.x] = lds[255];
  int pre = (t==0) ? 0 : lds[t-1];
  int4 o;
  o.x = pre; o.y = o.x+v.x; o.z = o.y+v.y; o.w = o.z+v.z;
  *(int4*)(out + base) = o;
}

__global__ void scan2_k(int* __restrict__ bsum){
  __shared__ int lds[256];
  int t = threadIdx.x;
  int2 v = *(const int2*)(bsum + t*2);
  lds[t] = v.x+v.y;
  __syncthreads();
  for (int off=1; off<256; off<<=1){
    int x = (t>=off) ? lds[t-off] : 0;
    __syncthreads();
    lds[t] += x;
    __syncthreads();
  }
  int pre = (t==0) ? 0 : lds[t-1];
  int2 o; o.x = pre; o.y = pre + v.x;
  *(int2*)(bsum + t*2) = o;
}

__global__ void scan3_k(int* __restrict__ out, const int* __restrict__ bsum){
  int t = threadIdx.x;
  int base = blockIdx.x*1024 + t*4;
  int add = bsum[blockIdx.x];
  int4 v = *(int4*)(out + base);
  v.x+=add; v.y+=add; v.z+=add; v.w+=add;
  *(int4*)(out + base) = v;
}

// fill consumes off via atomicAdd: afterwards off[key] == end(key), so
// start(key) = (key==0) ? 0 : off[key-1].
__global__ void fill_k(const int* __restrict__ et, const int* __restrict__ ec,
                       const float* __restrict__ me, int* __restrict__ off,
                       uint2* __restrict__ erec){
  int e = blockIdx.x*256 + threadIdx.x;
  int b = e >> 17;
  int src = et[2*e];
  int dst = et[2*e+1];
  int r  = ec[e];
  int key = (((b<<4)+r)<<13) + dst;
  int pos = atomicAdd(&off[key], 1);
  erec[pos] = make_uint2((unsigned)src, __float_as_uint(me[e]));
}

// ---------------- feature prep (embed + 3x W-transpose, fused) ------------

__global__ void prep_k(const int* __restrict__ cls, const float* __restrict__ emb,
                       const float* __restrict__ W1, const float* __restrict__ W2,
                       const float* __restrict__ W3,
                       unsigned short* __restrict__ h,
                       unsigned short* __restrict__ W1t,
                       unsigned short* __restrict__ W2t,
                       unsigned short* __restrict__ W3t){
  int t = blockIdx.x*256 + threadIdx.x;
  if (t < B_*N_*32) {
    int node = t>>5, c = t&31;
    int cl = cls[node];
    float4 v = *(const float4*)(emb + cl*H_ + c*4);
    uint2 o;
    o.x = f2bf(v.x) | ((unsigned int)f2bf(v.y)<<16);
    o.y = f2bf(v.z) | ((unsigned int)f2bf(v.w)<<16);
    *(uint2*)(h + node*H_ + c*4) = o;
  } else {
    int u = t - B_*N_*32;
    if (u < R_*H_*H_) {
      int k = u & 127, n = (u>>7) & 127, r = u >> 14;
      W1t[u] = f2bf(W1[(r*H_ + k)*H_ + n]);
    } else if (u < 2*R_*H_*H_) {
      int u2 = u - R_*H_*H_;
      int k = u2 & 127, n = (u2>>7) & 127, r = u2 >> 14;
      W2t[u2] = f2bf(W2[(r*H_ + k)*H_ + n]);
    } else {
      int u2 = u - 2*R_*H_*H_;
      if (u2 < R_*OUT_*H_) {
        int k = u2 & 127, n = (u2>>7) & 31, r = u2 >> 12;
        W3t[u2] = f2bf(W3[(r*H_ + k)*OUT_ + n]);
      }
    }
  }
}

// ---------------- fused layer: TLP aggregate panel -> K-split GEMM --------
// Block = 32 dst rows, 512 threads (8 waves), 1 block/CU (148KB LDS).
// Phase 1: thread = (row, rel) pair (32x16 = 512): edge-sums its full
//   128-feat row in 4 slices of 32 fp32 regs (independent 16B loads),
//   writes bf16 to A-panel [32][2048] in LDS, XOR-swizzled by (row^rel)&7.
// Phase 2: dense GEMM K=2048, K-split: wave w owns rels {2w, 2w+1}.
//   Per wave: 16 A ds_reads + B-frags streamed from L2 (addresses
//   independent -> deep pipeline) + MFMAs; stagger-offset LDS atomic
//   combine of the 8 K-partials. 3 barriers total, no per-rel sync.

template<int NOUT>
__global__ __launch_bounds__(512, 2) void layer_k(
    const unsigned short* __restrict__ h_in,   // bf16 [B*N*H]
    const unsigned short* __restrict__ Wt,     // bf16 [R][NOUT][H]
    const int* __restrict__ off,               // post-fill: off[key] = end(key)
    const uint2* __restrict__ erec,            // {src, mask bits}
    unsigned short* __restrict__ h_out,        // bf16 relu'd (NOUT=128)
    float* __restrict__ logits)                // fp32 (NOUT=32)
{
  constexpr int NI   = NOUT/16;                // 8 or 2
  constexpr int CST  = NOUT + 4;               // comb stride (floats)
  __shared__ __align__(16) unsigned short A_s[32*2048];  // 128 KB
  __shared__ float comb[32*CST];
  __shared__ int rowoff_s[16*33];              // [rel][33] starts

  const int tid  = threadIdx.x;
  const int lane = tid & 63;
  const int w    = tid >> 6;
  const int c16  = lane & 15;
  const int g    = lane >> 4;

  // XCD-batch affinity (grid 1024, bijective): xcd = orig&7 -> b = xcd>>1
  const int orig = blockIdx.x;
  const int xcd  = orig & 7;
  const int b    = xcd >> 1;
  const int dst0 = (((xcd & 1) << 7) + (orig >> 3)) << 5;   // tile*32
  const char* hbB = (const char*)h_in + ((size_t)b << 21);  // b*N*H*2B

  // init: row offsets (start of each key) + zero comb
  for (int i = tid; i < 16*33; i += 512) {
    int rel = i / 33, rr = i - rel*33;
    int key = (((b<<4) + rel) << 13) + dst0 + rr;
    rowoff_s[i] = (key == 0) ? 0 : off[key-1];
  }
  for (int i = tid; i < 32*CST; i += 512) comb[i] = 0.f;
  __syncthreads();

  // ---- phase 1: aggregate one (row, rel) pair per thread ----
  {
    const int row = tid >> 4;
    const int rel = tid & 15;
    int s0 = rowoff_s[rel*33 + row];
    int s1 = rowoff_s[rel*33 + row + 1];
    int cnt = s1 - s0;
    uint2 r0, r1;
    if (cnt > 0) r0 = erec[s0];
    if (cnt > 1) r1 = erec[s0+1];
    const unsigned swx = (unsigned)(((row ^ rel) & 7) << 4);
    char* arow = (char*)A_s + (row << 12);
    const int relbase = rel << 8;               // rel*128 feats * 2B

#define UNP8(FP, V, M) do { \
  (FP)[0]+=M*bfh((V).x,0); (FP)[1]+=M*bfh((V).x,1); \
  (FP)[2]+=M*bfh((V).y,0); (FP)[3]+=M*bfh((V).y,1); \
  (FP)[4]+=M*bfh((V).z,0); (FP)[5]+=M*bfh((V).z,1); \
  (FP)[6]+=M*bfh((V).w,0); (FP)[7]+=M*bfh((V).w,1); \
} while(0)
#define MAC32(FA, RC, FO) do { \
  float m_ = __uint_as_float((RC).y); \
  const char* hp_ = hbB + ((size_t)(RC).x << 8) + (FO); \
  uint4 v0_ = *(const uint4*)(hp_); \
  uint4 v1_ = *(const uint4*)(hp_ + 16); \
  uint4 v2_ = *(const uint4*)(hp_ + 32); \
  uint4 v3_ = *(const uint4*)(hp_ + 48); \
  UNP8((FA)+0, v0_, m_); UNP8((FA)+8, v1_, m_); \
  UNP8((FA)+16, v2_, m_); UNP8((FA)+24, v3_, m_); \
} while(0)

    for (int sl = 0; sl < 4; ++sl) {
      float fa[32];
      #pragma unroll
      for (int u = 0; u < 32; ++u) fa[u] = 0.f;
      const int fo = sl << 6;                   // byte offset into h row
      if (cnt > 0) MAC32(fa, r0, fo);
      if (cnt > 1) MAC32(fa, r1, fo);
      for (int e = s0+2; e < s1; ++e) { uint2 rc = erec[e]; MAC32(fa, rc, fo); }
      #pragma unroll
      for (int c = 0; c < 4; ++c) {
        uint4 pk;
        pk.x = cvtpk(fa[c*8+0], fa[c*8+1]);
        pk.y = cvtpk(fa[c*8+2], fa[c*8+3]);
        pk.z = cvtpk(fa[c*8+4], fa[c*8+5]);
        pk.w = cvtpk(fa[c*8+6], fa[c*8+7]);
        *(uint4*)(arow + ((unsigned)(relbase + (sl<<6) + (c<<4)) ^ swx)) = pk;
      }
    }
#undef MAC32
#undef UNP8
  }
  __syncthreads();

  // ---- phase 2: K-split GEMM (wave w: rels 2w, 2w+1) ----
  f32x4 acc[2][NI];
  #pragma unroll
  for (int mi=0; mi<2; ++mi)
    #pragma unroll
    for (int ni=0; ni<NI; ++ni)
      acc[mi][ni] = f32x4{0.f,0.f,0.f,0.f};

  #pragma unroll
  for (int kf = 0; kf < 8; ++kf) {
    const int rel = 2*w + (kf >> 2);
    const int inner = ((kf & 3) << 6) + (g << 4);       // byte within rel's 256B
    const unsigned sw0 = (unsigned)(((c16 ^ rel) & 7) << 4);
    const unsigned bo  = (unsigned)((rel << 8) + inner);
    short8 a0 = *(const short8*)((const char*)A_s + (c16 << 12)        + (bo ^ sw0));
    short8 a1 = *(const short8*)((const char*)A_s + ((c16+16) << 12)   + (bo ^ sw0));
    const unsigned short* Wr = Wt + (((size_t)rel * NOUT) << 7) + ((kf & 3) << 5) + (g << 3);
    #pragma unroll
    for (int ni = 0; ni < NI; ++ni) {
      short8 bq = *(const short8*)(Wr + ((ni*16 + c16) << 7));
      acc[0][ni] = __builtin_amdgcn_mfma_f32_16x16x32_bf16(a0, bq, acc[0][ni], 0,0,0);
      acc[1][ni] = __builtin_amdgcn_mfma_f32_16x16x32_bf16(a1, bq, acc[1][ni], 0,0,0);
    }
  }

  // stagger-offset LDS atomic combine of the 8 K-partials
  #pragma unroll
  for (int ii = 0; ii < NI; ++ii) {
    const int ni = (ii + w) & (NI - 1);
    #pragma unroll
    for (int mi = 0; mi < 2; ++mi)
      #pragma unroll
      for (int j = 0; j < 4; ++j)
        atomicAdd(&comb[(mi*16 + g*4 + j)*CST + ni*16 + c16], acc[mi][ni][j]);
  }
  __syncthreads();

  // ---- epilogue ----
  if constexpr (NOUT == 128) {
    const int row = tid >> 4;                 // 0..31
    const int c0  = (tid & 15) << 3;          // 8 cols
    const size_t node = (size_t)((b<<13) + dst0 + row);
    const float* cp = &comb[row*CST + c0];
    float4 x0 = *(const float4*)(cp);
    float4 x1 = *(const float4*)(cp + 4);
    uint4 pk;
    pk.x = cvtpk(fmaxf(x0.x,0.f), fmaxf(x0.y,0.f));
    pk.y = cvtpk(fmaxf(x0.z,0.f), fmaxf(x0.w,0.f));
    pk.z = cvtpk(fmaxf(x1.x,0.f), fmaxf(x1.y,0.f));
    pk.w = cvtpk(fmaxf(x1.z,0.f), fmaxf(x1.w,0.f));
    *(uint4*)(h_out + (node << 7) + c0) = pk;
  } else {
    if (tid < 256) {
      const int row = tid >> 3;               // 0..31
      const int c0  = (tid & 7) << 2;
      const size_t node = (size_t)((b<<13) + dst0 + row);
      float4 vv = *(const float4*)&comb[row*CST + c0];
      *(float4*)(logits + (node << 5) + c0) = vv;
    }
  }
}

__global__ void softmax_k(const float* __restrict__ logits,
                          const float* __restrict__ mobj,
                          float* __restrict__ out){
  int row = blockIdx.x*256 + threadIdx.x;  // 32768 rows
  float v[32];
  const float4* p = (const float4*)(logits + row*32);
  #pragma unroll
  for (int i=0;i<8;i++){
    float4 x = p[i];
    v[4*i]=x.x; v[4*i+1]=x.y; v[4*i+2]=x.z; v[4*i+3]=x.w;
  }
  float mx = v[0];
  #pragma unroll
  for (int i=1;i<32;i++) mx = fmaxf(mx, v[i]);
  float s = 0.f;
  #pragma unroll
  for (int i=0;i<32;i++){ v[i] = __expf(v[i]-mx); s += v[i]; }
  float sc = mobj[row] / s;
  float4* qo = (float4*)(out + row*32);
  #pragma unroll
  for (int i=0;i<8;i++){
    float4 x;
    x.x=v[4*i]*sc; x.y=v[4*i+1]*sc; x.z=v[4*i+2]*sc; x.w=v[4*i+3]*sc;
    qo[i] = x;
  }
}

extern "C" void kernel_launch(void* const* d_in, const int* in_sizes, int n_in,
                              void* d_out, int out_size, void* d_ws, size_t ws_size,
                              hipStream_t stream){
  const int*   cls   = (const int*)  d_in[0];
  // d_in[1] states_objects: unused by reference
  const int*   et    = (const int*)  d_in[2];
  const int*   ec    = (const int*)  d_in[3];
  const float* mobj  = (const float*)d_in[4];
  const float* medge = (const float*)d_in[5];
  const float* emb   = (const float*)d_in[6];
  const float* W1    = (const float*)d_in[7];
  const float* W2    = (const float*)d_in[8];
  const float* W3    = (const float*)d_in[9];
  float* out = (float*)d_out;

  char* ws = (char*)d_ws;
  size_t o = 0;
  auto alloc = [&](size_t bytes)->char*{
    char* p = ws + o;
    o += (bytes + 255) & ~(size_t)255;
    return p;
  };
  unsigned short* hA    = (unsigned short*)alloc((size_t)B_*N_*H_*2);
  unsigned short* hB    = (unsigned short*)alloc((size_t)B_*N_*H_*2);
  float*          lg    = (float*)alloc((size_t)B_*N_*OUT_*4);
  unsigned short* W1t   = (unsigned short*)alloc((size_t)R_*H_*H_*2);
  unsigned short* W2t   = (unsigned short*)alloc((size_t)R_*H_*H_*2);
  unsigned short* W3t   = (unsigned short*)alloc((size_t)R_*OUT_*H_*2);
  int*            cnt   = (int*)alloc((size_t)NKEYS*4);
  int*            off   = (int*)alloc((size_t)(NKEYS+1)*4);
  int*            bsum  = (int*)alloc(512*4);
  uint2*          erec  = (uint2*)alloc((size_t)NEDGE*8);
  (void)ws_size; (void)in_sizes; (void)n_in; (void)out_size;

  // CSR build: histogram -> exclusive scan -> fill (fill consumes off)
  hipMemsetAsync(cnt, 0, (size_t)NKEYS*4, stream);
  hipLaunchKernelGGL(hist_k,  dim3(NEDGE/256), dim3(256), 0, stream, et, ec, cnt);
  hipLaunchKernelGGL(scan1_k, dim3(512), dim3(256), 0, stream, cnt, off, bsum);
  hipLaunchKernelGGL(scan2_k, dim3(1),   dim3(256), 0, stream, bsum);
  hipLaunchKernelGGL(scan3_k, dim3(512), dim3(256), 0, stream, off, bsum);
  hipLaunchKernelGGL(fill_k,  dim3(NEDGE/256), dim3(256), 0, stream, et, ec, medge, off, erec);

  // h0 = bf16(embed[class]);  W -> bf16 [r][n][k]  (fused)
  hipLaunchKernelGGL(prep_k, dim3((B_*N_*32 + 2*R_*H_*H_ + R_*OUT_*H_)/256), dim3(256), 0, stream,
                     cls, emb, W1, W2, W3, hA, W1t, W2t, W3t);

  // 3 fused aggregate+GEMM layers, then softmax*mask
  hipLaunchKernelGGL((layer_k<128>), dim3(B_*N_/32), dim3(512), 0, stream,
                     hA, W1t, off, erec, hB, (float*)nullptr);
  hipLaunchKernelGGL((layer_k<128>), dim3(B_*N_/32), dim3(512), 0, stream,
                     hB, W2t, off, erec, hA, (float*)nullptr);
  hipLaunchKernelGGL((layer_k<32>),  dim3(B_*N_/32), dim3(512), 0, stream,
                     hA, W3t, off, erec, (unsigned short*)nullptr, lg);
  hipLaunchKernelGGL(softmax_k, dim3(B_*N_/256), dim3(256), 0, stream, lg, mobj, out);
}

// Round 7
// 312.770 us; speedup vs baseline: 2.3609x; 2.3609x over previous
//
#include <hip/hip_runtime.h>

typedef __attribute__((ext_vector_type(4))) float f32x4;
typedef __attribute__((ext_vector_type(8))) short short8;

#define B_ 4
#define N_ 8192
#define E_ 131072
#define R_ 16
#define H_ 128
#define OUT_ 32
#define NKEYS (B_*N_*R_)   /* 524288 */
#define NEDGE (B_*E_)      /* 524288 */

__device__ __forceinline__ unsigned short f2bf(float f){
  unsigned int u = __float_as_uint(f);
  u = (u + 0x7fffu + ((u>>16)&1u)) >> 16;
  return (unsigned short)u;
}
__device__ __forceinline__ float bfh(unsigned u, int hi){
  return __uint_as_float(hi ? (u & 0xffff0000u) : (u << 16));
}
__device__ __forceinline__ unsigned cvtpk(float lo, float hi){
  unsigned r;
  asm("v_cvt_pk_bf16_f32 %0, %1, %2" : "=v"(r) : "v"(lo), "v"(hi));
  return r;
}
__device__ __forceinline__ void glds16(const void* g, void* l){
  __builtin_amdgcn_global_load_lds((const __attribute__((address_space(1))) unsigned int*)g,
                                   (__attribute__((address_space(3))) unsigned int*)l,
                                   16, 0, 0);
}

// ---------------- CSR build: key = (((b<<13)+dst)<<4) + rel ----------------

__global__ void hist_k(const int* __restrict__ et, const int* __restrict__ ec,
                       int* __restrict__ cnt){
  int e = blockIdx.x*256 + threadIdx.x;
  int b = e >> 17;                  // E = 2^17
  int dst = et[2*e+1];
  int r  = ec[e];
  atomicAdd(&cnt[(((b<<13)+dst)<<4) + r], 1);
}

__global__ void scan1_k(const int* __restrict__ in, int* __restrict__ out,
                        int* __restrict__ bsum){
  __shared__ int lds[256];
  int t = threadIdx.x;
  int base = blockIdx.x*1024 + t*4;
  int4 v = *(const int4*)(in + base);
  lds[t] = v.x+v.y+v.z+v.w;
  __syncthreads();
  for (int off=1; off<256; off<<=1){
    int x = (t>=off) ? lds[t-off] : 0;
    __syncthreads();
    lds[t] += x;
    __syncthreads();
  }
  if (t==255) bsum[blockIdx.x] = lds[255];
  int pre = (t==0) ? 0 : lds[t-1];
  int4 o;
  o.x = pre; o.y = o.x+v.x; o.z = o.y+v.y; o.w = o.z+v.z;
  *(int4*)(out + base) = o;
}

__global__ void scan2_k(int* __restrict__ bsum){
  __shared__ int lds[256];
  int t = threadIdx.x;
  int2 v = *(const int2*)(bsum + t*2);
  lds[t] = v.x+v.y;
  __syncthreads();
  for (int off=1; off<256; off<<=1){
    int x = (t>=off) ? lds[t-off] : 0;
    __syncthreads();
    lds[t] += x;
    __syncthreads();
  }
  int pre = (t==0) ? 0 : lds[t-1];
  int2 o; o.x = pre; o.y = pre + v.x;
  *(int2*)(bsum + t*2) = o;
}

__global__ void scan3_k(int* __restrict__ out, const int* __restrict__ bsum){
  int t = threadIdx.x;
  int base = blockIdx.x*1024 + t*4;
  int add = bsum[blockIdx.x];
  int4 v = *(int4*)(out + base);
  v.x+=add; v.y+=add; v.z+=add; v.w+=add;
  *(int4*)(out + base) = v;
}

// fill consumes off via atomicAdd: afterwards off[key] == end(key);
// start(key) = (key==0) ? 0 : off[key-1].
__global__ void fill_k(const int* __restrict__ et, const int* __restrict__ ec,
                       const float* __restrict__ me, int* __restrict__ off,
                       uint2* __restrict__ erec){
  int e = blockIdx.x*256 + threadIdx.x;
  int b = e >> 17;
  int src = et[2*e];
  int dst = et[2*e+1];
  int r  = ec[e];
  int key = (((b<<13)+dst)<<4) + r;
  int pos = atomicAdd(&off[key], 1);
  erec[pos] = make_uint2((unsigned)src, __float_as_uint(me[e]));
}

// ---------------- feature prep (embed + 3x W-transpose, fused) ------------

__global__ void prep_k(const int* __restrict__ cls, const float* __restrict__ emb,
                       const float* __restrict__ W1, const float* __restrict__ W2,
                       const float* __restrict__ W3,
                       unsigned short* __restrict__ h,
                       unsigned short* __restrict__ W1t,
                       unsigned short* __restrict__ W2t,
                       unsigned short* __restrict__ W3t){
  int t = blockIdx.x*256 + threadIdx.x;
  if (t < B_*N_*32) {
    int node = t>>5, c = t&31;
    int cl = cls[node];
    float4 v = *(const float4*)(emb + cl*H_ + c*4);
    uint2 o;
    o.x = f2bf(v.x) | ((unsigned int)f2bf(v.y)<<16);
    o.y = f2bf(v.z) | ((unsigned int)f2bf(v.w)<<16);
    *(uint2*)(h + node*H_ + c*4) = o;
  } else {
    int u = t - B_*N_*32;
    if (u < R_*H_*H_) {
      int k = u & 127, n = (u>>7) & 127, r = u >> 14;
      W1t[u] = f2bf(W1[(r*H_ + k)*H_ + n]);
    } else if (u < 2*R_*H_*H_) {
      int u2 = u - R_*H_*H_;
      int k = u2 & 127, n = (u2>>7) & 127, r = u2 >> 14;
      W2t[u2] = f2bf(W2[(r*H_ + k)*H_ + n]);
    } else {
      int u2 = u - 2*R_*H_*H_;
      if (u2 < R_*OUT_*H_) {
        int k = u2 & 127, n = (u2>>7) & 31, r = u2 >> 12;
        W3t[u2] = f2bf(W3[(r*H_ + k)*OUT_ + n]);
      }
    }
  }
}

// ---------------- aggregation: agg[(b,dst,rel)][128] = sum mask*h[src] ----
// One thread per (key, 32-feat quarter): 2M independent threads, no
// barriers, no MFMA coupling -> TLP hides all gather latency. Writes are
// fully coalesced (4 threads = 256B per key, keys consecutive).

__global__ __launch_bounds__(256) void agg_k(
    const unsigned short* __restrict__ h_in,   // bf16 [B*N*H]
    const int* __restrict__ off,               // post-fill: off[key] = end
    const uint2* __restrict__ erec,
    unsigned short* __restrict__ agg){         // bf16 [B*N][R*H]
  int tg = blockIdx.x*256 + threadIdx.x;       // 2,097,152
  int key = tg >> 2;
  int q   = tg & 3;
  int b   = key >> 17;
  int s0 = key ? off[key-1] : 0;
  int s1 = off[key];
  const unsigned short* hb = h_in + ((size_t)b << 20);

  float fa[32];
  #pragma unroll
  for (int i=0;i<32;++i) fa[i] = 0.f;

#define UNP8(FP, V, M) do { \
  (FP)[0]+=M*bfh((V).x,0); (FP)[1]+=M*bfh((V).x,1); \
  (FP)[2]+=M*bfh((V).y,0); (FP)[3]+=M*bfh((V).y,1); \
  (FP)[4]+=M*bfh((V).z,0); (FP)[5]+=M*bfh((V).z,1); \
  (FP)[6]+=M*bfh((V).w,0); (FP)[7]+=M*bfh((V).w,1); \
} while(0)

  for (int e = s0; e < s1; ++e) {
    uint2 rc = erec[e];
    float m = __uint_as_float(rc.y);
    const uint4* hp = (const uint4*)(hb + (((unsigned)rc.x)<<7) + (q<<5));
    uint4 v0 = hp[0], v1 = hp[1], v2 = hp[2], v3 = hp[3];
    UNP8(fa+0,  v0, m); UNP8(fa+8,  v1, m);
    UNP8(fa+16, v2, m); UNP8(fa+24, v3, m);
  }
#undef UNP8

  unsigned short* ap = agg + ((size_t)key << 7) + (q<<5);
  #pragma unroll
  for (int c = 0; c < 4; ++c) {
    uint4 pk;
    pk.x = cvtpk(fa[c*8+0], fa[c*8+1]);
    pk.y = cvtpk(fa[c*8+2], fa[c*8+3]);
    pk.z = cvtpk(fa[c*8+4], fa[c*8+5]);
    pk.w = cvtpk(fa[c*8+6], fa[c*8+7]);
    *(uint4*)(ap + c*8) = pk;
  }
}

// ---------------- dense GEMM: C[32768, NOUT] = agg[32768,2048] @ W --------
// M-tile 128, BK=64, A+B dbuf via global_load_lds (pre-swizzled source),
// counted vmcnt + raw s_barrier so prefetch stays in flight across
// barriers (T4). NOUT=128: relu+bf16 out. NOUT=32: fused softmax*mask.

template<int NOUT>
__global__ __launch_bounds__(512, 2) void gemm_k(
    const unsigned short* __restrict__ Ag,     // bf16 [32768][2048]
    const unsigned short* __restrict__ Wt,     // bf16 [R][NOUT][H]
    const float* __restrict__ mobj,            // [B*N] (NOUT=32)
    unsigned short* __restrict__ h_out,        // bf16 (NOUT=128)
    float* __restrict__ out)                   // fp32 (NOUT=32)
{
  constexpr int MI  = (NOUT==128) ? 2 : 1;
  constexpr int NIw = (NOUT==128) ? 4 : 2;
  __shared__ __align__(16) unsigned short A_s[2][128*64];   // 2 x 16 KB
  __shared__ __align__(16) unsigned short B_s[2][NOUT*64];  // 2 x 16/4 KB

  const int tid  = threadIdx.x;
  const int lane = tid & 63;
  const int w    = tid >> 6;
  const int c16  = lane & 15;
  const int g    = lane >> 4;
  const int m0   = blockIdx.x << 7;
  const int mbase = (NOUT==128) ? ((w>>1)<<5) : (w<<4);
  const int nbase = (NOUT==128) ? ((w&1)<<6) : 0;

#define STAGE(KC, BUF) do { \
  const int kc_ = (KC); \
  _Pragma("unroll") \
  for (int i_=0;i_<2;++i_){ \
    int uid_ = ((w*2+i_)<<6) + lane; \
    int m_ = uid_>>3, u_ = uid_&7; \
    const char* src_ = (const char*)Ag + (((size_t)(m0+m_))<<12) + (kc_<<7) \
                     + ((u_ ^ (m_&7))<<4); \
    glds16(src_, &A_s[BUF][(w*2+i_)<<9]); \
  } \
  if constexpr (NOUT==128) { \
    _Pragma("unroll") \
    for (int i_=0;i_<2;++i_){ \
      int uid_ = ((w*2+i_)<<6) + lane; \
      int n_ = uid_>>3, u_ = uid_&7; \
      const char* src_ = (const char*)Wt + ((size_t)(((kc_>>1)*128 + n_)<<8)) \
                       + ((kc_&1)<<7) + ((u_ ^ (n_&7))<<4); \
      glds16(src_, &B_s[BUF][(w*2+i_)<<9]); \
    } \
  } else { \
    if (w < 4) { \
      int uid_ = (w<<6) + lane; \
      int n_ = uid_>>3, u_ = uid_&7; \
      const char* src_ = (const char*)Wt + ((size_t)(((kc_>>1)*32 + n_)<<8)) \
                       + ((kc_&1)<<7) + ((u_ ^ (n_&7))<<4); \
      glds16(src_, &B_s[BUF][w<<9]); \
    } \
  } \
} while(0)

#define WAIT_PREV do { \
  if constexpr (NOUT==128) { asm volatile("s_waitcnt vmcnt(4)" ::: "memory"); } \
  else { if (w < 4) asm volatile("s_waitcnt vmcnt(3)" ::: "memory"); \
         else       asm volatile("s_waitcnt vmcnt(2)" ::: "memory"); } \
} while(0)

  f32x4 acc[MI][NIw];
  #pragma unroll
  for (int mi=0; mi<MI; ++mi)
    #pragma unroll
    for (int ni=0; ni<NIw; ++ni)
      acc[mi][ni] = f32x4{0.f,0.f,0.f,0.f};

#define COMPUTE(BUF) do { \
  _Pragma("unroll") \
  for (int kk=0; kk<2; ++kk) { \
    short8 af[MI], bf[NIw]; \
    _Pragma("unroll") \
    for (int mi=0; mi<MI; ++mi) { \
      int m_ = mbase + mi*16 + c16; \
      af[mi] = *(const short8*)((const char*)A_s[BUF] + m_*128 \
               + (((kk<<6) + (g<<4)) ^ ((m_&7)<<4))); \
    } \
    _Pragma("unroll") \
    for (int ni=0; ni<NIw; ++ni) { \
      int n_ = nbase + ni*16 + c16; \
      bf[ni] = *(const short8*)((const char*)B_s[BUF] + n_*128 \
               + (((kk<<6) + (g<<4)) ^ ((n_&7)<<4))); \
    } \
    _Pragma("unroll") \
    for (int mi=0; mi<MI; ++mi) \
      _Pragma("unroll") \
      for (int ni=0; ni<NIw; ++ni) \
        acc[mi][ni] = __builtin_amdgcn_mfma_f32_16x16x32_bf16(af[mi], bf[ni], acc[mi][ni], 0,0,0); \
  } \
} while(0)

  STAGE(0, 0);
  for (int kc = 0; kc < 31; ++kc) {
    const int cur = kc & 1;
    STAGE(kc+1, cur^1);
    WAIT_PREV;
    __builtin_amdgcn_s_barrier();
    COMPUTE(cur);
    asm volatile("s_waitcnt lgkmcnt(0)" ::: "memory");
    __builtin_amdgcn_s_barrier();
  }
  asm volatile("s_waitcnt vmcnt(0)" ::: "memory");
  __builtin_amdgcn_s_barrier();
  COMPUTE(1);

  if constexpr (NOUT == 128) {
    #pragma unroll
    for (int mi=0; mi<MI; ++mi)
      #pragma unroll
      for (int ni=0; ni<NIw; ++ni)
        #pragma unroll
        for (int j=0; j<4; ++j) {
          int row = mbase + mi*16 + g*4 + j;
          int col = nbase + ni*16 + c16;
          h_out[((size_t)(m0+row)<<7) + col] = f2bf(fmaxf(acc[mi][ni][j], 0.f));
        }
  } else {
    #pragma unroll
    for (int j=0; j<4; ++j) {
      int row = mbase + g*4 + j;
      float v0 = acc[0][0][j], v1 = acc[0][1][j];
      float mx = fmaxf(v0, v1);
      #pragma unroll
      for (int s=8; s>0; s>>=1) mx = fmaxf(mx, __shfl_xor(mx, s, 16));
      float e0 = __expf(v0 - mx), e1 = __expf(v1 - mx);
      float sm = e0 + e1;
      #pragma unroll
      for (int s=8; s>0; s>>=1) sm += __shfl_xor(sm, s, 16);
      float sc = mobj[m0+row] / sm;
      out[((size_t)(m0+row)<<5) + c16]      = e0*sc;
      out[((size_t)(m0+row)<<5) + 16 + c16] = e1*sc;
    }
  }
#undef STAGE
#undef WAIT_PREV
#undef COMPUTE
}

extern "C" void kernel_launch(void* const* d_in, const int* in_sizes, int n_in,
                              void* d_out, int out_size, void* d_ws, size_t ws_size,
                              hipStream_t stream){
  const int*   cls   = (const int*)  d_in[0];
  // d_in[1] states_objects: unused by reference
  const int*   et    = (const int*)  d_in[2];
  const int*   ec    = (const int*)  d_in[3];
  const float* mobj  = (const float*)d_in[4];
  const float* medge = (const float*)d_in[5];
  const float* emb   = (const float*)d_in[6];
  const float* W1    = (const float*)d_in[7];
  const float* W2    = (const float*)d_in[8];
  const float* W3    = (const float*)d_in[9];
  float* out = (float*)d_out;

  char* ws = (char*)d_ws;
  size_t o = 0;
  auto alloc = [&](size_t bytes)->char*{
    char* p = ws + o;
    o += (bytes + 255) & ~(size_t)255;
    return p;
  };
  unsigned short* hA    = (unsigned short*)alloc((size_t)B_*N_*H_*2);
  unsigned short* hB    = (unsigned short*)alloc((size_t)B_*N_*H_*2);
  unsigned short* W1t   = (unsigned short*)alloc((size_t)R_*H_*H_*2);
  unsigned short* W2t   = (unsigned short*)alloc((size_t)R_*H_*H_*2);
  unsigned short* W3t   = (unsigned short*)alloc((size_t)R_*OUT_*H_*2);
  int*            cnt   = (int*)alloc((size_t)NKEYS*4);
  int*            off   = (int*)alloc((size_t)NKEYS*4);
  int*            bsum  = (int*)alloc(512*4);
  uint2*          erec  = (uint2*)alloc((size_t)NEDGE*8);
  unsigned short* agg   = (unsigned short*)alloc((size_t)B_*N_*R_*H_*2);  // 128 MB
  (void)ws_size; (void)in_sizes; (void)n_in; (void)out_size;

  // CSR build: histogram -> exclusive scan -> fill (fill consumes off)
  hipMemsetAsync(cnt, 0, (size_t)NKEYS*4, stream);
  hipLaunchKernelGGL(hist_k,  dim3(NEDGE/256), dim3(256), 0, stream, et, ec, cnt);
  hipLaunchKernelGGL(scan1_k, dim3(512), dim3(256), 0, stream, cnt, off, bsum);
  hipLaunchKernelGGL(scan2_k, dim3(1),   dim3(256), 0, stream, bsum);
  hipLaunchKernelGGL(scan3_k, dim3(512), dim3(256), 0, stream, off, bsum);
  hipLaunchKernelGGL(fill_k,  dim3(NEDGE/256), dim3(256), 0, stream, et, ec, medge, off, erec);

  // h0 = bf16(embed[class]);  W -> bf16 [r][n][k]
  hipLaunchKernelGGL(prep_k, dim3((B_*N_*32 + 2*R_*H_*H_ + R_*OUT_*H_)/256), dim3(256), 0, stream,
                     cls, emb, W1, W2, W3, hA, W1t, W2t, W3t);

  const int aggGrid  = (NKEYS*4)/256;   // 8192
  const int gemmGrid = (B_*N_)/128;     // 256

  // layer 1
  hipLaunchKernelGGL(agg_k, dim3(aggGrid), dim3(256), 0, stream, hA, off, erec, agg);
  hipLaunchKernelGGL((gemm_k<128>), dim3(gemmGrid), dim3(512), 0, stream,
                     agg, W1t, (const float*)nullptr, hB, (float*)nullptr);
  // layer 2
  hipLaunchKernelGGL(agg_k, dim3(aggGrid), dim3(256), 0, stream, hB, off, erec, agg);
  hipLaunchKernelGGL((gemm_k<128>), dim3(gemmGrid), dim3(512), 0, stream,
                     agg, W2t, (const float*)nullptr, hA, (float*)nullptr);
  // layer 3 (+ fused softmax * mask)
  hipLaunchKernelGGL(agg_k, dim3(aggGrid), dim3(256), 0, stream, hA, off, erec, agg);
  hipLaunchKernelGGL((gemm_k<32>), dim3(gemmGrid), dim3(512), 0, stream,
                     agg, W3t, mobj, (unsigned short*)nullptr, out);
}

// Round 8
// 282.372 us; speedup vs baseline: 2.6150x; 1.1077x over previous
//
#include <hip/hip_runtime.h>

typedef __attribute__((ext_vector_type(4))) float f32x4;
typedef __attribute__((ext_vector_type(8))) short short8;

#define B_ 4
#define N_ 8192
#define E_ 131072
#define R_ 16
#define H_ 128
#define OUT_ 32
#define NKEYS (B_*N_*R_)   /* 524288 */
#define NEDGE (B_*E_)      /* 524288 */

__device__ __forceinline__ unsigned short f2bf(float f){
  unsigned int u = __float_as_uint(f);
  u = (u + 0x7fffu + ((u>>16)&1u)) >> 16;
  return (unsigned short)u;
}
__device__ __forceinline__ float bfh(unsigned u, int hi){
  return __uint_as_float(hi ? (u & 0xffff0000u) : (u << 16));
}
__device__ __forceinline__ unsigned cvtpk(float lo, float hi){
  unsigned r;
  asm("v_cvt_pk_bf16_f32 %0, %1, %2" : "=v"(r) : "v"(lo), "v"(hi));
  return r;
}
__device__ __forceinline__ void glds16(const void* g, void* l){
  __builtin_amdgcn_global_load_lds((const __attribute__((address_space(1))) unsigned int*)g,
                                   (__attribute__((address_space(3))) unsigned int*)l,
                                   16, 0, 0);
}

// ---------------- CSR build: key = node*16 + rel, node = b*8192+dst -------

__global__ void hist_k(const int* __restrict__ et, const int* __restrict__ ec,
                       int* __restrict__ cnt){
  int e = blockIdx.x*256 + threadIdx.x;
  int b = e >> 17;                  // E = 2^17
  int dst = et[2*e+1];
  int r  = ec[e];
  atomicAdd(&cnt[(((b<<13)+dst)<<4) + r], 1);
}

__global__ void scan1_k(const int* __restrict__ in, int* __restrict__ out,
                        int* __restrict__ bsum){
  __shared__ int lds[256];
  int t = threadIdx.x;
  int base = blockIdx.x*1024 + t*4;
  int4 v = *(const int4*)(in + base);
  lds[t] = v.x+v.y+v.z+v.w;
  __syncthreads();
  for (int off=1; off<256; off<<=1){
    int x = (t>=off) ? lds[t-off] : 0;
    __syncthreads();
    lds[t] += x;
    __syncthreads();
  }
  if (t==255) bsum[blockIdx.x] = lds[255];
  int pre = (t==0) ? 0 : lds[t-1];
  int4 o;
  o.x = pre; o.y = o.x+v.x; o.z = o.y+v.y; o.w = o.z+v.z;
  *(int4*)(out + base) = o;
}

// scan over flags (cnt != 0)
__global__ void scan1b_k(const int* __restrict__ cnt, int* __restrict__ out,
                         int* __restrict__ bsum){
  __shared__ int lds[256];
  int t = threadIdx.x;
  int base = blockIdx.x*1024 + t*4;
  int4 v = *(const int4*)(cnt + base);
  int4 f; f.x = v.x!=0; f.y = v.y!=0; f.z = v.z!=0; f.w = v.w!=0;
  lds[t] = f.x+f.y+f.z+f.w;
  __syncthreads();
  for (int off=1; off<256; off<<=1){
    int x = (t>=off) ? lds[t-off] : 0;
    __syncthreads();
    lds[t] += x;
    __syncthreads();
  }
  if (t==255) bsum[blockIdx.x] = lds[255];
  int pre = (t==0) ? 0 : lds[t-1];
  int4 o;
  o.x = pre; o.y = o.x+f.x; o.z = o.y+f.y; o.w = o.z+f.z;
  *(int4*)(out + base) = o;
}

__global__ void scan2_k(int* __restrict__ bsum){
  __shared__ int lds[256];
  int t = threadIdx.x;
  int2 v = *(const int2*)(bsum + t*2);
  lds[t] = v.x+v.y;
  __syncthreads();
  for (int off=1; off<256; off<<=1){
    int x = (t>=off) ? lds[t-off] : 0;
    __syncthreads();
    lds[t] += x;
    __syncthreads();
  }
  int pre = (t==0) ? 0 : lds[t-1];
  int2 o; o.x = pre; o.y = pre + v.x;
  *(int2*)(bsum + t*2) = o;
}

__global__ void scan3_k(int* __restrict__ out, const int* __restrict__ bsum){
  int t = threadIdx.x;
  int base = blockIdx.x*1024 + t*4;
  int add = bsum[blockIdx.x];
  int4 v = *(int4*)(out + base);
  v.x+=add; v.y+=add; v.z+=add; v.w+=add;
  *(int4*)(out + base) = v;
}

// cmap[key] = (cnt>0) ? 1 + exclusive_prefix(flags) : 0   (slot 0 = zeros)
__global__ void scan3b_k(const int* __restrict__ cidx, const int* __restrict__ bsum,
                         const int* __restrict__ cnt, int* __restrict__ cmap){
  int t = threadIdx.x;
  int base = blockIdx.x*1024 + t*4;
  int add = bsum[blockIdx.x] + 1;
  int4 cx = *(const int4*)(cidx + base);
  int4 cv = *(const int4*)(cnt + base);
  int4 o;
  o.x = cv.x ? cx.x+add : 0;
  o.y = cv.y ? cx.y+add : 0;
  o.z = cv.z ? cx.z+add : 0;
  o.w = cv.w ? cx.w+add : 0;
  *(int4*)(cmap + base) = o;
}

// fill consumes off via atomicAdd: afterwards off[key] == end(key);
// start(key) = (key==0) ? 0 : off[key-1].
__global__ void fill_k(const int* __restrict__ et, const int* __restrict__ ec,
                       const float* __restrict__ me, int* __restrict__ off,
                       uint2* __restrict__ erec){
  int e = blockIdx.x*256 + threadIdx.x;
  int b = e >> 17;
  int src = et[2*e];
  int dst = et[2*e+1];
  int r  = ec[e];
  int key = (((b<<13)+dst)<<4) + r;
  int pos = atomicAdd(&off[key], 1);
  erec[pos] = make_uint2((unsigned)src, __float_as_uint(me[e]));
}

// ---------------- feature prep (embed + 3x W-transpose + zero slot) -------

__global__ void prep_k(const int* __restrict__ cls, const float* __restrict__ emb,
                       const float* __restrict__ W1, const float* __restrict__ W2,
                       const float* __restrict__ W3,
                       unsigned short* __restrict__ h,
                       unsigned short* __restrict__ W1t,
                       unsigned short* __restrict__ W2t,
                       unsigned short* __restrict__ W3t,
                       unsigned short* __restrict__ aggc){
  int t = blockIdx.x*256 + threadIdx.x;
  if (blockIdx.x == 0 && threadIdx.x < 16) {
    *(uint4*)((char*)aggc + threadIdx.x*16) = make_uint4(0,0,0,0);  // zero slot
  }
  if (t < B_*N_*32) {
    int node = t>>5, c = t&31;
    int cl = cls[node];
    float4 v = *(const float4*)(emb + cl*H_ + c*4);
    uint2 o;
    o.x = f2bf(v.x) | ((unsigned int)f2bf(v.y)<<16);
    o.y = f2bf(v.z) | ((unsigned int)f2bf(v.w)<<16);
    *(uint2*)(h + node*H_ + c*4) = o;
  } else {
    int u = t - B_*N_*32;
    if (u < R_*H_*H_) {
      int k = u & 127, n = (u>>7) & 127, r = u >> 14;
      W1t[u] = f2bf(W1[(r*H_ + k)*H_ + n]);
    } else if (u < 2*R_*H_*H_) {
      int u2 = u - R_*H_*H_;
      int k = u2 & 127, n = (u2>>7) & 127, r = u2 >> 14;
      W2t[u2] = f2bf(W2[(r*H_ + k)*H_ + n]);
    } else {
      int u2 = u - 2*R_*H_*H_;
      if (u2 < R_*OUT_*H_) {
        int k = u2 & 127, n = (u2>>7) & 31, r = u2 >> 12;
        W3t[u2] = f2bf(W3[(r*H_ + k)*OUT_ + n]);
      }
    }
  }
}

// ---------------- aggregation (compacted): agg_c[cmap[key]] = sum ---------
// One thread per (key, 32-feat quarter); empty keys exit immediately (37%).
// 2-deep edge-record prefetch shortens the dependent-load chain.

__global__ __launch_bounds__(256) void agg_k(
    const unsigned short* __restrict__ h_in,   // bf16 [B*N*H]
    const int* __restrict__ off,               // post-fill: off[key] = end
    const int* __restrict__ cmap,
    const uint2* __restrict__ erec,
    unsigned short* __restrict__ aggc){        // bf16 [1+nz][128]
  int tg = blockIdx.x*256 + threadIdx.x;       // 2,097,152
  int key = tg >> 2;
  int q   = tg & 3;
  int s0 = key ? off[key-1] : 0;
  int s1 = off[key];
  if (s1 == s0) return;
  int cm = cmap[key];
  int b  = key >> 17;
  const unsigned short* hb = h_in + ((size_t)b << 20);

  float fa[32];
  #pragma unroll
  for (int i=0;i<32;++i) fa[i] = 0.f;

#define UNP8(FP, V, M) do { \
  (FP)[0]+=M*bfh((V).x,0); (FP)[1]+=M*bfh((V).x,1); \
  (FP)[2]+=M*bfh((V).y,0); (FP)[3]+=M*bfh((V).y,1); \
  (FP)[4]+=M*bfh((V).z,0); (FP)[5]+=M*bfh((V).z,1); \
  (FP)[6]+=M*bfh((V).w,0); (FP)[7]+=M*bfh((V).w,1); \
} while(0)
#define MAC32(RC) do { \
  float m_ = __uint_as_float((RC).y); \
  const uint4* hp_ = (const uint4*)(hb + (((unsigned)(RC).x)<<7) + (q<<5)); \
  uint4 v0_ = hp_[0], v1_ = hp_[1], v2_ = hp_[2], v3_ = hp_[3]; \
  UNP8(fa+0,  v0_, m_); UNP8(fa+8,  v1_, m_); \
  UNP8(fa+16, v2_, m_); UNP8(fa+24, v3_, m_); \
} while(0)

  int cnt = s1 - s0;
  uint2 rA = erec[s0];
  uint2 rB;
  if (cnt > 1) rB = erec[s0+1];
  MAC32(rA);
  if (cnt > 1) MAC32(rB);
  for (int e = s0+2; e < s1; ++e) { uint2 rc = erec[e]; MAC32(rc); }
#undef MAC32
#undef UNP8

  unsigned short* ap = aggc + ((size_t)cm << 7) + (q<<5);
  #pragma unroll
  for (int c = 0; c < 4; ++c) {
    uint4 pk;
    pk.x = cvtpk(fa[c*8+0], fa[c*8+1]);
    pk.y = cvtpk(fa[c*8+2], fa[c*8+3]);
    pk.z = cvtpk(fa[c*8+4], fa[c*8+5]);
    pk.w = cvtpk(fa[c*8+6], fa[c*8+7]);
    *(uint4*)(ap + c*8) = pk;
  }
}

// ---------------- dense GEMM over compacted A -----------------------------
// M-tile 128, BK=64, A staged via cmap indirection (empty rows -> zero
// slot; glds stays wave-uniform, vmcnt count untouched since cmap comes
// from LDS). Counted vmcnt + raw s_barrier (T4). NOUT=32 fuses softmax.

template<int NOUT>
__global__ __launch_bounds__(512, 2) void gemm_k(
    const unsigned short* __restrict__ Agc,    // bf16 [1+nz][128]
    const int* __restrict__ cmap,              // [NKEYS]
    const unsigned short* __restrict__ Wt,     // bf16 [R][NOUT][H]
    const float* __restrict__ mobj,            // [B*N] (NOUT=32)
    unsigned short* __restrict__ h_out,        // bf16 (NOUT=128)
    float* __restrict__ out)                   // fp32 (NOUT=32)
{
  constexpr int MI  = (NOUT==128) ? 2 : 1;
  constexpr int NIw = (NOUT==128) ? 4 : 2;
  __shared__ __align__(16) unsigned short A_s[2][128*64];   // 2 x 16 KB
  __shared__ __align__(16) unsigned short B_s[2][NOUT*64];  // 2 x 16/4 KB
  __shared__ int cmap_s[128*16];                            // 8 KB

  const int tid  = threadIdx.x;
  const int lane = tid & 63;
  const int w    = tid >> 6;
  const int c16  = lane & 15;
  const int g    = lane >> 4;
  const int m0   = blockIdx.x << 7;
  const int mbase = (NOUT==128) ? ((w>>1)<<5) : (w<<4);
  const int nbase = (NOUT==128) ? ((w&1)<<6) : 0;

  // prologue: this block's 2048 consecutive cmap entries -> LDS
  *(int4*)&cmap_s[tid<<2] = *(const int4*)(cmap + ((size_t)m0<<4) + (tid<<2));
  __syncthreads();

#define STAGE(KC, BUF) do { \
  const int kc_ = (KC); \
  _Pragma("unroll") \
  for (int i_=0;i_<2;++i_){ \
    int uid_ = ((w*2+i_)<<6) + lane; \
    int m_ = uid_>>3, u_ = uid_&7; \
    int cm_ = cmap_s[(m_<<4) + (kc_>>1)]; \
    const char* src_ = (const char*)Agc + ((size_t)cm_<<8) + ((kc_&1)<<7) \
                     + ((u_ ^ (m_&7))<<4); \
    glds16(src_, &A_s[BUF][(w*2+i_)<<9]); \
  } \
  if constexpr (NOUT==128) { \
    _Pragma("unroll") \
    for (int i_=0;i_<2;++i_){ \
      int uid_ = ((w*2+i_)<<6) + lane; \
      int n_ = uid_>>3, u_ = uid_&7; \
      const char* src_ = (const char*)Wt + ((size_t)(((kc_>>1)*128 + n_)<<8)) \
                       + ((kc_&1)<<7) + ((u_ ^ (n_&7))<<4); \
      glds16(src_, &B_s[BUF][(w*2+i_)<<9]); \
    } \
  } else { \
    if (w < 4) { \
      int uid_ = (w<<6) + lane; \
      int n_ = uid_>>3, u_ = uid_&7; \
      const char* src_ = (const char*)Wt + ((size_t)(((kc_>>1)*32 + n_)<<8)) \
                       + ((kc_&1)<<7) + ((u_ ^ (n_&7))<<4); \
      glds16(src_, &B_s[BUF][w<<9]); \
    } \
  } \
} while(0)

#define WAIT_PREV do { \
  if constexpr (NOUT==128) { asm volatile("s_waitcnt vmcnt(4)" ::: "memory"); } \
  else { if (w < 4) asm volatile("s_waitcnt vmcnt(3)" ::: "memory"); \
         else       asm volatile("s_waitcnt vmcnt(2)" ::: "memory"); } \
} while(0)

  f32x4 acc[MI][NIw];
  #pragma unroll
  for (int mi=0; mi<MI; ++mi)
    #pragma unroll
    for (int ni=0; ni<NIw; ++ni)
      acc[mi][ni] = f32x4{0.f,0.f,0.f,0.f};

#define COMPUTE(BUF) do { \
  _Pragma("unroll") \
  for (int kk=0; kk<2; ++kk) { \
    short8 af[MI], bf[NIw]; \
    _Pragma("unroll") \
    for (int mi=0; mi<MI; ++mi) { \
      int m_ = mbase + mi*16 + c16; \
      af[mi] = *(const short8*)((const char*)A_s[BUF] + m_*128 \
               + (((kk<<6) + (g<<4)) ^ ((m_&7)<<4))); \
    } \
    _Pragma("unroll") \
    for (int ni=0; ni<NIw; ++ni) { \
      int n_ = nbase + ni*16 + c16; \
      bf[ni] = *(const short8*)((const char*)B_s[BUF] + n_*128 \
               + (((kk<<6) + (g<<4)) ^ ((n_&7)<<4))); \
    } \
    _Pragma("unroll") \
    for (int mi=0; mi<MI; ++mi) \
      _Pragma("unroll") \
      for (int ni=0; ni<NIw; ++ni) \
        acc[mi][ni] = __builtin_amdgcn_mfma_f32_16x16x32_bf16(af[mi], bf[ni], acc[mi][ni], 0,0,0); \
  } \
} while(0)

  STAGE(0, 0);
  for (int kc = 0; kc < 31; ++kc) {
    const int cur = kc & 1;
    STAGE(kc+1, cur^1);
    WAIT_PREV;
    __builtin_amdgcn_s_barrier();
    COMPUTE(cur);
    asm volatile("s_waitcnt lgkmcnt(0)" ::: "memory");
    __builtin_amdgcn_s_barrier();
  }
  asm volatile("s_waitcnt vmcnt(0)" ::: "memory");
  __builtin_amdgcn_s_barrier();
  COMPUTE(1);

  if constexpr (NOUT == 128) {
    #pragma unroll
    for (int mi=0; mi<MI; ++mi)
      #pragma unroll
      for (int ni=0; ni<NIw; ++ni)
        #pragma unroll
        for (int j=0; j<4; ++j) {
          int row = mbase + mi*16 + g*4 + j;
          int col = nbase + ni*16 + c16;
          h_out[((size_t)(m0+row)<<7) + col] = f2bf(fmaxf(acc[mi][ni][j], 0.f));
        }
  } else {
    #pragma unroll
    for (int j=0; j<4; ++j) {
      int row = mbase + g*4 + j;
      float v0 = acc[0][0][j], v1 = acc[0][1][j];
      float mx = fmaxf(v0, v1);
      #pragma unroll
      for (int s=8; s>0; s>>=1) mx = fmaxf(mx, __shfl_xor(mx, s, 16));
      float e0 = __expf(v0 - mx), e1 = __expf(v1 - mx);
      float sm = e0 + e1;
      #pragma unroll
      for (int s=8; s>0; s>>=1) sm += __shfl_xor(sm, s, 16);
      float sc = mobj[m0+row] / sm;
      out[((size_t)(m0+row)<<5) + c16]      = e0*sc;
      out[((size_t)(m0+row)<<5) + 16 + c16] = e1*sc;
    }
  }
#undef STAGE
#undef WAIT_PREV
#undef COMPUTE
}

extern "C" void kernel_launch(void* const* d_in, const int* in_sizes, int n_in,
                              void* d_out, int out_size, void* d_ws, size_t ws_size,
                              hipStream_t stream){
  const int*   cls   = (const int*)  d_in[0];
  // d_in[1] states_objects: unused by reference
  const int*   et    = (const int*)  d_in[2];
  const int*   ec    = (const int*)  d_in[3];
  const float* mobj  = (const float*)d_in[4];
  const float* medge = (const float*)d_in[5];
  const float* emb   = (const float*)d_in[6];
  const float* W1    = (const float*)d_in[7];
  const float* W2    = (const float*)d_in[8];
  const float* W3    = (const float*)d_in[9];
  float* out = (float*)d_out;

  char* ws = (char*)d_ws;
  size_t o = 0;
  auto alloc = [&](size_t bytes)->char*{
    char* p = ws + o;
    o += (bytes + 255) & ~(size_t)255;
    return p;
  };
  unsigned short* hA    = (unsigned short*)alloc((size_t)B_*N_*H_*2);
  unsigned short* hB    = (unsigned short*)alloc((size_t)B_*N_*H_*2);
  unsigned short* W1t   = (unsigned short*)alloc((size_t)R_*H_*H_*2);
  unsigned short* W2t   = (unsigned short*)alloc((size_t)R_*H_*H_*2);
  unsigned short* W3t   = (unsigned short*)alloc((size_t)R_*OUT_*H_*2);
  int*            cnt   = (int*)alloc((size_t)NKEYS*4);
  int*            off   = (int*)alloc((size_t)NKEYS*4);
  int*            cidx  = (int*)alloc((size_t)NKEYS*4);
  int*            cmap  = (int*)alloc((size_t)NKEYS*4);
  int*            bsum  = (int*)alloc(512*4);
  int*            bsum2 = (int*)alloc(512*4);
  uint2*          erec  = (uint2*)alloc((size_t)NEDGE*8);
  unsigned short* aggc  = (unsigned short*)alloc(((size_t)NKEYS+1)*H_*2);  // 128 MB
  (void)ws_size; (void)in_sizes; (void)n_in; (void)out_size;

  // CSR build + compaction map
  hipMemsetAsync(cnt, 0, (size_t)NKEYS*4, stream);
  hipLaunchKernelGGL(hist_k,   dim3(NEDGE/256), dim3(256), 0, stream, et, ec, cnt);
  hipLaunchKernelGGL(scan1_k,  dim3(512), dim3(256), 0, stream, cnt, off, bsum);
  hipLaunchKernelGGL(scan2_k,  dim3(1),   dim3(256), 0, stream, bsum);
  hipLaunchKernelGGL(scan3_k,  dim3(512), dim3(256), 0, stream, off, bsum);
  hipLaunchKernelGGL(scan1b_k, dim3(512), dim3(256), 0, stream, cnt, cidx, bsum2);
  hipLaunchKernelGGL(scan2_k,  dim3(1),   dim3(256), 0, stream, bsum2);
  hipLaunchKernelGGL(scan3b_k, dim3(512), dim3(256), 0, stream, cidx, bsum2, cnt, cmap);
  hipLaunchKernelGGL(fill_k,   dim3(NEDGE/256), dim3(256), 0, stream, et, ec, medge, off, erec);

  // h0 = bf16(embed[class]);  W -> bf16 [r][n][k];  zero slot 0 of aggc
  hipLaunchKernelGGL(prep_k, dim3((B_*N_*32 + 2*R_*H_*H_ + R_*OUT_*H_)/256), dim3(256), 0, stream,
                     cls, emb, W1, W2, W3, hA, W1t, W2t, W3t, aggc);

  const int aggGrid  = (NKEYS*4)/256;   // 8192
  const int gemmGrid = (B_*N_)/128;     // 256

  // layer 1
  hipLaunchKernelGGL(agg_k, dim3(aggGrid), dim3(256), 0, stream, hA, off, cmap, erec, aggc);
  hipLaunchKernelGGL((gemm_k<128>), dim3(gemmGrid), dim3(512), 0, stream,
                     aggc, cmap, W1t, (const float*)nullptr, hB, (float*)nullptr);
  // layer 2
  hipLaunchKernelGGL(agg_k, dim3(aggGrid), dim3(256), 0, stream, hB, off, cmap, erec, aggc);
  hipLaunchKernelGGL((gemm_k<128>), dim3(gemmGrid), dim3(512), 0, stream,
                     aggc, cmap, W2t, (const float*)nullptr, hA, (float*)nullptr);
  // layer 3 (+ fused softmax * mask)
  hipLaunchKernelGGL(agg_k, dim3(aggGrid), dim3(256), 0, stream, hA, off, cmap, erec, aggc);
  hipLaunchKernelGGL((gemm_k<32>), dim3(gemmGrid), dim3(512), 0, stream,
                     aggc, cmap, W3t, mobj, (unsigned short*)nullptr, out);
}